// Round 3
// baseline (161.669 us; speedup 1.0000x reference)
//
#include <hip/hip_runtime.h>
#include <math.h>

#define B_   32
#define M_   32
#define P_   196
#define D_   20
#define O_   16
#define I_   8
#define DO_  320    // D*O
#define PD_  3920   // P*D
#define ROW_ 62720  // P*DO

#define CMAPS_OFF 10240
#define FEAT_OFF  4024320

__device__ __forceinline__ unsigned short f2bf(float v) {
    unsigned int u = __float_as_uint(v);
    return (unsigned short)((u + 0x7fffu + ((u >> 16) & 1u)) >> 16);
}
__device__ __forceinline__ unsigned int pk2(float lo, float hi) {
    return (unsigned int)f2bf(lo) | ((unsigned int)f2bf(hi) << 16);
}
__device__ __forceinline__ float bfhi(unsigned int w) { return __uint_as_float(w & 0xffff0000u); }
__device__ __forceinline__ float bflo(unsigned int w) { return __uint_as_float(w << 16); }

// ---------------- K1: u_hat = W.x, store bf16 (packed dwordx4 stores) -------
// grid: M * 49 (p-tiles of 4), 320 threads.
// thread: g = t%40 owns do in [g*8, g*8+8); bq = t/40 owns b = bq*4+bb.
#define PT4  4
#define NPT4 49
__global__ __launch_bounds__(320)
void caps_u(const float* __restrict__ x, const float* __restrict__ W,
            unsigned short* __restrict__ uh)
{
    __shared__ float x_lds[PT4 * 260];   // [p][b*8+i], stride 260 (16B-aligned)
    const int m  = blockIdx.x / NPT4;
    const int pt = blockIdx.x % NPT4;
    const int p0 = pt * PT4;
    const int t  = threadIdx.x;
    const int g  = t % 40;
    const int bq = t / 40;

    if (t < 256) {
        int p = t >> 6, b = (t >> 1) & 31, h = t & 1;
        *(float4*)(x_lds + p * 260 + b * 8 + h * 4) =
            *(const float4*)(x + (((size_t)b * M_ + m) * P_ + p0 + p) * I_ + h * 4);
    }
    __syncthreads();

    #pragma unroll 1
    for (int pl = 0; pl < PT4; pl++) {
        const float* wp = W + ((size_t)(m * P_ + p0 + pl) * DO_ + g * 8) * I_;
        float w[64];
        #pragma unroll
        for (int q = 0; q < 16; q++)
            *(float4*)(w + q * 4) = *(const float4*)(wp + q * 4);
        #pragma unroll
        for (int bb = 0; bb < 4; bb++) {
            const int b = bq * 4 + bb;
            float xr[8];
            *(float4*)(xr)     = *(const float4*)(x_lds + pl * 260 + b * 8);
            *(float4*)(xr + 4) = *(const float4*)(x_lds + pl * 260 + b * 8 + 4);
            float u[8];
            #pragma unroll
            for (int r = 0; r < 8; r++) {
                float s = w[r * 8] * xr[0];
                #pragma unroll
                for (int i = 1; i < 8; i++) s = fmaf(w[r * 8 + i], xr[i], s);
                u[r] = s;
            }
            uint4 pkv;
            pkv.x = pk2(u[0], u[1]); pkv.y = pk2(u[2], u[3]);
            pkv.z = pk2(u[4], u[5]); pkv.w = pk2(u[6], u[7]);
            *(uint4*)(uh + (((size_t)b * M_ + m) * P_ + p0 + pl) * DO_ + g * 8) = pkv;
        }
    }
}

// ---------------- route: one block per (b,m) row of u_hat ----------------
// MODE 0: s1 partial (uniform c, unscaled sum; /PD applied in squash)
// MODE 1: online-softmax s partial (blog = u.v)
// MODE 2: same + c_maps + features outputs
// thread t: d = t%20, chunk k = t/20 (16 chunks over P), owns full o in regs.
template<int MODE>
__global__ __launch_bounds__(320)
void route_k(const unsigned short* __restrict__ uh, const float* __restrict__ vin,
             float* __restrict__ pbm, float* __restrict__ out)
{
    extern __shared__ float sm[];
    float* accL  = sm;               // [320*17]
    float* red   = sm + 320 * 17;    // [16]
    float* blogL = red + 16;         // [3920] (MODE2)
    float* usqL  = blogL + 3920;     // [3920] (MODE2)

    const int blk = blockIdx.x;      // b*32 + m
    const int t = threadIdx.x;
    const int d = t % 20;
    const int k = t / 20;
    const int pstart = k * 12 + (k < 4 ? k : 4);
    const int pcnt   = (k < 4) ? 13 : 12;
    const unsigned short* up = uh + (size_t)blk * ROW_;

    float vreg[16];
    if (MODE) {
        const float* vb = vin + (size_t)(blk >> 5) * DO_;
        #pragma unroll
        for (int o = 0; o < 16; o++) vreg[o] = vb[d * 16 + o];
    }
    float acc[16];
    #pragma unroll
    for (int o = 0; o < 16; o++) acc[o] = 0.f;
    float mloc = -1e30f, Z = 0.f;

    for (int pp = 0; pp < pcnt; pp++) {
        const int p = pstart + pp;
        const float4* a = (const float4*)(up + (size_t)p * DO_ + d * 16);
        float4 a0 = a[0], a1 = a[1];
        unsigned int ua[8];
        ua[0]=__float_as_uint(a0.x); ua[1]=__float_as_uint(a0.y);
        ua[2]=__float_as_uint(a0.z); ua[3]=__float_as_uint(a0.w);
        ua[4]=__float_as_uint(a1.x); ua[5]=__float_as_uint(a1.y);
        ua[6]=__float_as_uint(a1.z); ua[7]=__float_as_uint(a1.w);
        float u[16];
        #pragma unroll
        for (int q = 0; q < 8; q++) { u[2*q] = bflo(ua[q]); u[2*q+1] = bfhi(ua[q]); }

        if (MODE) {
            float bl = u[0] * vreg[0];
            #pragma unroll
            for (int o = 1; o < 16; o++) bl = fmaf(u[o], vreg[o], bl);
            if (MODE == 2) {
                float us = u[0] * u[0];
                #pragma unroll
                for (int o = 1; o < 16; o++) us = fmaf(u[o], u[o], us);
                blogL[p * D_ + d] = bl;
                usqL[p * D_ + d]  = us;
            }
            if (bl > mloc + 8.f) {           // defer-max rescale (T13)
                float r = __expf(mloc - bl);
                Z *= r;
                #pragma unroll
                for (int o = 0; o < 16; o++) acc[o] *= r;
                mloc = bl;
            }
            float e = __expf(bl - mloc);
            Z += e;
            #pragma unroll
            for (int o = 0; o < 16; o++) acc[o] = fmaf(e, u[o], acc[o]);
        } else {
            #pragma unroll
            for (int o = 0; o < 16; o++) acc[o] += u[o];
        }
    }

    float f = 1.f, iz = 1.f, mx = 0.f;
    if (MODE) {
        mx = mloc;
        #pragma unroll
        for (int msk = 1; msk < 64; msk <<= 1) mx = fmaxf(mx, __shfl_xor(mx, msk, 64));
        if ((t & 63) == 0) red[t >> 6] = mx;
        __syncthreads();
        mx = fmaxf(fmaxf(fmaxf(red[0], red[1]), fmaxf(red[2], red[3])), red[4]);
        f = __expf(mloc - mx);
        float zz = Z * f;
        #pragma unroll
        for (int msk = 1; msk < 64; msk <<= 1) zz += __shfl_xor(zz, msk, 64);
        if ((t & 63) == 0) red[8 + (t >> 6)] = zz;
        __syncthreads();
        iz = 1.f / (red[8] + red[9] + red[10] + red[11] + red[12]);
    }
    #pragma unroll
    for (int o = 0; o < 16; o++) accL[t * 17 + o] = acc[o] * f;
    __syncthreads();
    {
        const int dd = t >> 4, oo = t & 15;
        float s = 0.f;
        #pragma unroll
        for (int kk = 0; kk < 16; kk++) s += accL[(kk * 20 + dd) * 17 + oo];
        s *= iz;
        pbm[(size_t)blk * DO_ + t] = s;
        if (MODE == 2) out[FEAT_OFF + (size_t)blk * DO_ + t] = s * (1.f / 196.f);
    }
    if (MODE == 2) {
        for (int e = t; e < PD_; e += 320)
            out[CMAPS_OFF + (size_t)blk * PD_ + e] =
                __expf(blogL[e] - mx) * iz * sqrtf(usqL[e]);
    }
}

// ---------------- squash: per b, sum partials over m ----------------
// WH 0: scale 1/PD, write v1. WH 1: write vs = v1 + v2. WH 2: write v to out.
template<int WH>
__global__ __launch_bounds__(320)
void sq2_k(const float* __restrict__ pbm, float* __restrict__ v1,
           float* __restrict__ vs, float* __restrict__ out)
{
    const int b = blockIdx.x, t = threadIdx.x;
    float s = 0.f;
    for (int mi = 0; mi < M_; mi++) s += pbm[((size_t)b * M_ + mi) * DO_ + t];
    if (WH == 0) s *= (1.f / PD_);
    float sq = s * s;
    #pragma unroll
    for (int msk = 1; msk < 16; msk <<= 1) sq += __shfl_xor(sq, msk, 16);
    float vr = (sq / (1.f + sq)) * s * rsqrtf(sq + 1e-9f);
    if (WH == 0) v1[(size_t)b * DO_ + t] = vr;
    if (WH == 1) vs[(size_t)b * DO_ + t] = v1[(size_t)b * DO_ + t] + vr;
    if (WH == 2) out[(size_t)b * DO_ + t] = vr;
}

extern "C" void kernel_launch(void* const* d_in, const int* in_sizes, int n_in,
                              void* d_out, int out_size, void* d_ws, size_t ws_size,
                              hipStream_t stream)
{
    const float* x = (const float*)d_in[0];
    const float* W = (const float*)d_in[1];
    float* out = (float*)d_out;

    unsigned short* uh = (unsigned short*)d_ws;
    // u_hat bf16: B*M*P*DO = 64,225,280 ushorts = 128,450,560 bytes
    float* fws = (float*)((char*)d_ws + (size_t)64225280 * 2);
    float* pbm = fws;                   // [B][M][DO] = 327,680 fl
    float* v1  = pbm + (size_t)B_ * M_ * DO_;
    float* vs  = v1 + (size_t)B_ * DO_;

    const size_t LDS_A = (320 * 17 + 16) * sizeof(float);
    const size_t LDS_B = LDS_A + 2 * PD_ * sizeof(float);

    caps_u<<<M_ * NPT4, 320, 0, stream>>>(x, W, uh);

    route_k<0><<<B_ * M_, 320, LDS_A, stream>>>(uh, v1, pbm, out);
    sq2_k<0><<<B_, 320, 0, stream>>>(pbm, v1, vs, out);

    route_k<1><<<B_ * M_, 320, LDS_A, stream>>>(uh, v1, pbm, out);
    sq2_k<1><<<B_, 320, 0, stream>>>(pbm, v1, vs, out);

    route_k<2><<<B_ * M_, 320, LDS_B, stream>>>(uh, vs, pbm, out);
    sq2_k<2><<<B_, 320, 0, stream>>>(pbm, v1, vs, out);
}

// Round 4
// 122.064 us; speedup vs baseline: 1.3245x; 1.3245x over previous
//
#include <hip/hip_runtime.h>
#include <math.h>

#define B_   32
#define M_   32
#define P_   196
#define D_   20
#define O_   16
#define I_   8
#define DO_  320    // D*O
#define PD_  3920   // P*D
#define ROW_ 62720  // P*DO

#define CMAPS_OFF 10240
#define FEAT_OFF  4024320

__device__ __forceinline__ unsigned short f2bf(float v) {
    unsigned int u = __float_as_uint(v);
    return (unsigned short)((u + 0x7fffu + ((u >> 16) & 1u)) >> 16);
}
__device__ __forceinline__ unsigned int pk2(float lo, float hi) {
    return (unsigned int)f2bf(lo) | ((unsigned int)f2bf(hi) << 16);
}
__device__ __forceinline__ float bfhi(unsigned int w) { return __uint_as_float(w & 0xffff0000u); }
__device__ __forceinline__ float bflo(unsigned int w) { return __uint_as_float(w << 16); }

// async global->LDS, 16B per lane; lds ptr must be wave-uniform base
__device__ __forceinline__ void gload16(const float* g, float* l) {
    __builtin_amdgcn_global_load_lds(
        (const __attribute__((address_space(1))) void*)g,
        (__attribute__((address_space(3))) void*)l, 16, 0, 0);
}

// ---------------- K1: u_hat = W.x -> bf16 ----------------
// grid: M*49 (p-tiles of 4), 320 threads (5 waves).
// W tile (10KB/pl) staged to LDS by global_load_lds, double-buffered,
// source-swizzled (s ^ ((s>>4)&7)) so ds_read_b128 is ~conflict-free.
// thread: g=t%40 owns do = {2g+80r, 2g+80r+1}, r=0..3 ; bq=t/40 owns 4 b.
#define CPT_ 4
#define CNT_ 49
__global__ __launch_bounds__(320)
void caps_u(const float* __restrict__ x, const float* __restrict__ W,
            unsigned short* __restrict__ uh)
{
    __shared__ float4 wb[2][640];        // 2 x 10,240 B
    __shared__ float  xl[1024];          // [b][pl*8+i] : 32 fl per b

    const int m  = blockIdx.x / CNT_;
    const int pt = blockIdx.x % CNT_;
    const int p0 = pt * CPT_;
    const int t  = threadIdx.x;
    const int g  = t % 40;
    const int bq = t / 40;
    const int wl = t & ~63;              // wave-uniform slot base (t = w*64+lane)

    if (t < 256) {
        int b = t >> 3, q = t & 7;
        *(float4*)(xl + b * 32 + q * 4) =
            *(const float4*)(x + (((size_t)b * M_ + m) * P_ + p0) * I_ + q * 4);
    }
    {   // prologue: stage pl=0
        const float* wsrc = W + (size_t)(m * P_ + p0) * 2560;
        int s0 = t, s1 = 320 + t;
        gload16(wsrc + (size_t)(s0 ^ ((s0 >> 4) & 7)) * 4, (float*)&wb[0][wl]);
        gload16(wsrc + (size_t)(s1 ^ ((s1 >> 4) & 7)) * 4, (float*)&wb[0][320 + wl]);
    }
    __syncthreads();

    for (int pl = 0; pl < CPT_; pl++) {
        if (pl < CPT_ - 1) {             // prefetch pl+1 into other buffer
            const float* wsrc = W + (size_t)(m * P_ + p0 + pl + 1) * 2560;
            int s0 = t, s1 = 320 + t;
            float* dst = (float*)&wb[(pl + 1) & 1][0];
            gload16(wsrc + (size_t)(s0 ^ ((s0 >> 4) & 7)) * 4, dst + (size_t)wl * 4);
            gload16(wsrc + (size_t)(s1 ^ ((s1 >> 4) & 7)) * 4, dst + (size_t)(320 + wl) * 4);
        }
        float xr[4][8];
        #pragma unroll
        for (int bb = 0; bb < 4; bb++) {
            *(float4*)(xr[bb])     = *(float4*)(xl + (bq * 4 + bb) * 32 + pl * 8);
            *(float4*)(xr[bb] + 4) = *(float4*)(xl + (bq * 4 + bb) * 32 + pl * 8 + 4);
        }
        const float4* wp = wb[pl & 1];
        #pragma unroll
        for (int r = 0; r < 4; r++) {
            const int gb = 4 * g + 160 * r;
            const int h  = (gb >> 4) & 7;
            float4 w0 = wp[(gb + 0) ^ h];
            float4 w1 = wp[(gb + 1) ^ h];
            float4 w2 = wp[(gb + 2) ^ h];
            float4 w3 = wp[(gb + 3) ^ h];
            const int do0 = 2 * g + 80 * r;
            #pragma unroll
            for (int bb = 0; bb < 4; bb++) {
                const float* a = xr[bb];
                float u0 = w0.x * a[0];
                u0 = fmaf(w0.y, a[1], u0); u0 = fmaf(w0.z, a[2], u0);
                u0 = fmaf(w0.w, a[3], u0); u0 = fmaf(w1.x, a[4], u0);
                u0 = fmaf(w1.y, a[5], u0); u0 = fmaf(w1.z, a[6], u0);
                u0 = fmaf(w1.w, a[7], u0);
                float u1 = w2.x * a[0];
                u1 = fmaf(w2.y, a[1], u1); u1 = fmaf(w2.z, a[2], u1);
                u1 = fmaf(w2.w, a[3], u1); u1 = fmaf(w3.x, a[4], u1);
                u1 = fmaf(w3.y, a[5], u1); u1 = fmaf(w3.z, a[6], u1);
                u1 = fmaf(w3.w, a[7], u1);
                *(unsigned int*)(uh + (((size_t)(bq * 4 + bb) * M_ + m) * P_
                                       + p0 + pl) * DO_ + do0) = pk2(u0, u1);
            }
        }
        __syncthreads();   // drains prefetch (vmcnt0) + guards buffer reuse
    }
}

// ---------------- route: one block per (b,m) row of u_hat ----------------
// MODE 0: s1 partial (uniform c). MODE 1: online-softmax s partial (blog=u.v)
// MODE 2: same + c_maps + features. thread: d=t%20, chunk k=t/20 over P.
template<int MODE>
__global__ __launch_bounds__(320)
void route_k(const unsigned short* __restrict__ uh, const float* __restrict__ vin,
             float* __restrict__ pbm, float* __restrict__ out)
{
    extern __shared__ float sm[];
    float* accL  = sm;               // [320*17]
    float* red   = sm + 320 * 17;    // [16]
    float* blogL = red + 16;         // [3920] (MODE2)
    float* usqL  = blogL + 3920;     // [3920] (MODE2)

    const int blk = blockIdx.x;      // b*32 + m
    const int t = threadIdx.x;
    const int d = t % 20;
    const int k = t / 20;
    const int pstart = k * 12 + (k < 4 ? k : 4);
    const int pcnt   = (k < 4) ? 13 : 12;
    const unsigned short* up = uh + (size_t)blk * ROW_;

    float vreg[16];
    if (MODE) {
        const float* vb = vin + (size_t)(blk >> 5) * DO_;
        #pragma unroll
        for (int o = 0; o < 16; o++) vreg[o] = vb[d * 16 + o];
    }
    float acc[16];
    #pragma unroll
    for (int o = 0; o < 16; o++) acc[o] = 0.f;
    float mloc = -1e30f, Z = 0.f;

    for (int pp = 0; pp < pcnt; pp++) {
        const int p = pstart + pp;
        const float4* a = (const float4*)(up + (size_t)p * DO_ + d * 16);
        float4 a0 = a[0], a1 = a[1];
        unsigned int ua[8];
        ua[0]=__float_as_uint(a0.x); ua[1]=__float_as_uint(a0.y);
        ua[2]=__float_as_uint(a0.z); ua[3]=__float_as_uint(a0.w);
        ua[4]=__float_as_uint(a1.x); ua[5]=__float_as_uint(a1.y);
        ua[6]=__float_as_uint(a1.z); ua[7]=__float_as_uint(a1.w);
        float u[16];
        #pragma unroll
        for (int q = 0; q < 8; q++) { u[2*q] = bflo(ua[q]); u[2*q+1] = bfhi(ua[q]); }

        if (MODE) {
            float bl = u[0] * vreg[0];
            #pragma unroll
            for (int o = 1; o < 16; o++) bl = fmaf(u[o], vreg[o], bl);
            if (MODE == 2) {
                float us = u[0] * u[0];
                #pragma unroll
                for (int o = 1; o < 16; o++) us = fmaf(u[o], u[o], us);
                blogL[p * D_ + d] = bl;
                usqL[p * D_ + d]  = us;
            }
            if (bl > mloc + 8.f) {           // defer-max rescale (T13)
                float r = __expf(mloc - bl);
                Z *= r;
                #pragma unroll
                for (int o = 0; o < 16; o++) acc[o] *= r;
                mloc = bl;
            }
            float e = __expf(bl - mloc);
            Z += e;
            #pragma unroll
            for (int o = 0; o < 16; o++) acc[o] = fmaf(e, u[o], acc[o]);
        } else {
            #pragma unroll
            for (int o = 0; o < 16; o++) acc[o] += u[o];
        }
    }

    float f = 1.f, iz = 1.f, mx = 0.f;
    if (MODE) {
        mx = mloc;
        #pragma unroll
        for (int msk = 1; msk < 64; msk <<= 1) mx = fmaxf(mx, __shfl_xor(mx, msk, 64));
        if ((t & 63) == 0) red[t >> 6] = mx;
        __syncthreads();
        mx = fmaxf(fmaxf(fmaxf(red[0], red[1]), fmaxf(red[2], red[3])), red[4]);
        f = __expf(mloc - mx);
        float zz = Z * f;
        #pragma unroll
        for (int msk = 1; msk < 64; msk <<= 1) zz += __shfl_xor(zz, msk, 64);
        if ((t & 63) == 0) red[8 + (t >> 6)] = zz;
        __syncthreads();
        iz = 1.f / (red[8] + red[9] + red[10] + red[11] + red[12]);
    }
    #pragma unroll
    for (int o = 0; o < 16; o++) accL[t * 17 + o] = acc[o] * f;
    __syncthreads();
    {
        const int dd = t >> 4, oo = t & 15;
        float s = 0.f;
        #pragma unroll
        for (int kk = 0; kk < 16; kk++) s += accL[(kk * 20 + dd) * 17 + oo];
        s *= iz;
        pbm[(size_t)blk * DO_ + t] = s;
        if (MODE == 2) out[FEAT_OFF + (size_t)blk * DO_ + t] = s * (1.f / 196.f);
    }
    if (MODE == 2) {
        for (int e = t; e < PD_; e += 320)
            out[CMAPS_OFF + (size_t)blk * PD_ + e] =
                __expf(blogL[e] - mx) * iz * sqrtf(usqL[e]);
    }
}

// ---------------- squash: per b, sum partials over m ----------------
template<int WH>
__global__ __launch_bounds__(320)
void sq2_k(const float* __restrict__ pbm, float* __restrict__ v1,
           float* __restrict__ vs, float* __restrict__ out)
{
    const int b = blockIdx.x, t = threadIdx.x;
    float s = 0.f;
    for (int mi = 0; mi < M_; mi++) s += pbm[((size_t)b * M_ + mi) * DO_ + t];
    if (WH == 0) s *= (1.f / PD_);
    float sq = s * s;
    #pragma unroll
    for (int msk = 1; msk < 16; msk <<= 1) sq += __shfl_xor(sq, msk, 16);
    float vr = (sq / (1.f + sq)) * s * rsqrtf(sq + 1e-9f);
    if (WH == 0) v1[(size_t)b * DO_ + t] = vr;
    if (WH == 1) vs[(size_t)b * DO_ + t] = v1[(size_t)b * DO_ + t] + vr;
    if (WH == 2) out[(size_t)b * DO_ + t] = vr;
}

extern "C" void kernel_launch(void* const* d_in, const int* in_sizes, int n_in,
                              void* d_out, int out_size, void* d_ws, size_t ws_size,
                              hipStream_t stream)
{
    const float* x = (const float*)d_in[0];
    const float* W = (const float*)d_in[1];
    float* out = (float*)d_out;

    unsigned short* uh = (unsigned short*)d_ws;   // bf16 u_hat: 128,450,560 B
    float* fws = (float*)((char*)d_ws + (size_t)64225280 * 2);
    float* pbm = fws;                             // [B][M][DO]
    float* v1  = pbm + (size_t)B_ * M_ * DO_;
    float* vs  = v1 + (size_t)B_ * DO_;

    const size_t LDS_A = (320 * 17 + 16) * sizeof(float);
    const size_t LDS_B = LDS_A + 2 * PD_ * sizeof(float);

    caps_u<<<M_ * CNT_, 320, 0, stream>>>(x, W, uh);

    route_k<0><<<B_ * M_, 320, LDS_A, stream>>>(uh, v1, pbm, out);
    sq2_k<0><<<B_, 320, 0, stream>>>(pbm, v1, vs, out);

    route_k<1><<<B_ * M_, 320, LDS_A, stream>>>(uh, v1, pbm, out);
    sq2_k<1><<<B_, 320, 0, stream>>>(pbm, v1, vs, out);

    route_k<2><<<B_ * M_, 320, LDS_B, stream>>>(uh, vs, pbm, out);
    sq2_k<2><<<B_, 320, 0, stream>>>(pbm, v1, vs, out);
}